// Round 12
// baseline (3327.930 us; speedup 1.0000x reference)
//
#include <hip/hip_runtime.h>
#include <stdint.h>

constexpr int kV = 128, kE = 100, kH = 1024, kB = 64, kT = 512, kH3 = 3072;

typedef __bf16 bf16_t;
typedef __bf16 bf16x8 __attribute__((ext_vector_type(8)));
typedef float f32x4 __attribute__((ext_vector_type(4)));
typedef unsigned int u32;
typedef unsigned long long u64;

// ---------------- P = emb @ Wx + b_in (+ b_rec for z,r gates) : [128][3072] f32
__global__ void k_prep_P(const float* __restrict__ emb, const float* __restrict__ Wx,
                         const float* __restrict__ b_in, const float* __restrict__ b_rec,
                         float* __restrict__ P) {
    const int n = blockIdx.x * 256 + threadIdx.x;   // 12 blocks.x * 256 = 3072
    const int v0 = blockIdx.y * 32;                 // 4 blocks.y
    float wcol[kE];
#pragma unroll
    for (int e = 0; e < kE; ++e) wcol[e] = Wx[e * kH3 + n];
    const float bias = b_in[n] + (n < 2 * kH ? b_rec[n] : 0.f);
    for (int vi = 0; vi < 32; ++vi) {
        const int v = v0 + vi;
        float acc = bias;
#pragma unroll
        for (int e = 0; e < kE; ++e) acc += emb[v * kE + e] * wcol[e];
        P[v * kH3 + n] = acc;
    }
}

// ---------------- WdT = bf16(Wd^T) : [128][1024]
__global__ void k_prep_WdT(const float* __restrict__ Wd, bf16_t* __restrict__ WdT) {
    const int i = blockIdx.x * 256 + threadIdx.x;   // 512 blocks -> 131072
    const int v = i & 127, k = i >> 7;
    WdT[v * kH + k] = (bf16_t)Wd[k * kV + v];
}

// ---------------- persistent GRU scan: r11-green structure, tag-in-data exchange.
// 256 WGs x 512 thr (8 waves). group g = blockIdx>>5 owns batch rows [8g,8g+8);
// slot = blockIdx&31 owns h-cols [32s,32s+32). h words: (bf16<<16)|tag, tag=t+1.
// Producers: relaxed-AGENT tagged stores only — NO vmcnt drain, NO flags (cuts
// 2 of the 4 per-step MALL hops measured in r11). Consumers, per 64B chunk
// (= one producer slot): phase-1 poll ONE 8B word (light — r10's collapse was
// 128B-per-retry poll traffic); phase-2 load+verify remaining 24B (rarely
// retries: a producer's stores land together). Per-lane independent retry.
// WAR depth-2 ring proof unchanged from r11: the per-step __syncthreads joins
// all 8 waves AFTER their polls (union = all 32 slots at tag >= t), so a
// wave's h[t] overwrite of h[t-2] follows every WG's completed reads of
// h[t-2]. Tags monotone per location; hsig memset per launch (in-graph) kills
// cross-replay aliasing.
__launch_bounds__(512, 1)
__global__ void k_scan(const int* __restrict__ tokens, const float* __restrict__ Uh,
                       const float* __restrict__ Pg, const float* __restrict__ b_rec,
                       u32* __restrict__ hsig, bf16_t* __restrict__ seq) {
    __shared__ float Pl[kV][104];          // [v][0:32)=z,[32:64)=r,[64:96)=hh
    __shared__ float part[2][8][8][104];   // [parity][kwave][row][gatecol 0:96)
    const int tid = threadIdx.x;
    const int g = blockIdx.x >> 5, slot = blockIdx.x & 31;
    const int c0 = slot * 32;
    const int lane = tid & 63, wave = tid >> 6;    // 0..7
    const int r16 = lane & 15, grp = lane >> 4;

    // stage P gather table for this WG's 96 gate columns (b_in/b_rec(z,r) folded)
    for (int idx = tid; idx < kV * 96; idx += 512) {
        const int v = idx / 96, gi = idx % 96;
        const int col = (gi >> 5) * kH + c0 + (gi & 31);
        Pl[v][gi] = Pg[v * kH3 + col];
    }
    // B-fragments: 6 tiles x 4 K-steps for this wave's K-slice, register-resident
    bf16x8 bf[6][4];
#pragma unroll
    for (int tile = 0; tile < 6; ++tile) {
        const int col = (tile >> 1) * kH + c0 + (tile & 1) * 16 + r16;
#pragma unroll
        for (int ks = 0; ks < 4; ++ks)
#pragma unroll
            for (int j = 0; j < 8; ++j)
                bf[tile][ks][j] = (bf16_t)Uh[(wave * 128 + ks * 32 + grp * 8 + j) * kH3 + col];
    }
    // gate-phase constants: wave w owns batch row 8g+w; lanes 0-7 x 4 cols at c4
    const int c4 = (lane & 7) * 4;
    const int myrow = 8 * g + wave;
    float brh4[4], hreg[4] = {0.f, 0.f, 0.f, 0.f};
#pragma unroll
    for (int i = 0; i < 4; ++i) brh4[i] = b_rec[2 * kH + c0 + c4 + i];
    int tokc = tokens[(size_t)myrow * kT + 0];
    const int arow = r16 & 7;                      // A-frag row (rows 8-15 dup)
    __syncthreads();

    for (int t = 0; t < kT; ++t) {
        if (t > 0) {
            // ---- tagged A-load: per-ks (= per producer slot) light poll + verify
            const u32 tag = (u32)t;
            const u32* hpar = hsig + (size_t)(((t - 1) & 1) * kB + 8 * g + arow) * kH;
            f32x4 acc[6];
#pragma unroll
            for (int tl = 0; tl < 6; ++tl) acc[tl] = (f32x4){0.f, 0.f, 0.f, 0.f};
#pragma unroll
            for (int ks = 0; ks < 4; ++ks) {
                const u64* bp = (const u64*)(hpar + wave * 128 + ks * 32 + grp * 8);
                u64 q0, q1, q2, q3;
                long guard = 0;
                for (;;) {   // phase 1: ONE 8B word (2 tags) — lightweight detect
                    q0 = __hip_atomic_load(bp, __ATOMIC_RELAXED, __HIP_MEMORY_SCOPE_AGENT);
                    if (((u32)q0 & 0xffffu) == tag && ((u32)(q0 >> 32) & 0xffffu) == tag) break;
                    __builtin_amdgcn_s_sleep(1);
                    if (++guard > (1L << 15)) break;   // anti-hang escape
                }
                guard = 0;
                for (;;) {   // phase 2: remaining 24B, verify 6 tags (rarely retries)
                    q1 = __hip_atomic_load(bp + 1, __ATOMIC_RELAXED, __HIP_MEMORY_SCOPE_AGENT);
                    q2 = __hip_atomic_load(bp + 2, __ATOMIC_RELAXED, __HIP_MEMORY_SCOPE_AGENT);
                    q3 = __hip_atomic_load(bp + 3, __ATOMIC_RELAXED, __HIP_MEMORY_SCOPE_AGENT);
                    const bool ok = ((u32)q1 & 0xffffu) == tag && ((u32)(q1 >> 32) & 0xffffu) == tag
                                 && ((u32)q2 & 0xffffu) == tag && ((u32)(q2 >> 32) & 0xffffu) == tag
                                 && ((u32)q3 & 0xffffu) == tag && ((u32)(q3 >> 32) & 0xffffu) == tag;
                    if (ok) break;
                    __builtin_amdgcn_s_sleep(1);
                    if (++guard > (1L << 12)) break;   // anti-hang escape
                }
                // unpack hi16 halves -> packed bf16 pairs (shift/and; no v_perm)
                union { u32 w[4]; bf16x8 v; } uv;
                uv.w[0] = ((u32)q0 >> 16) | ((u32)(q0 >> 32) & 0xffff0000u);
                uv.w[1] = ((u32)q1 >> 16) | ((u32)(q1 >> 32) & 0xffff0000u);
                uv.w[2] = ((u32)q2 >> 16) | ((u32)(q2 >> 32) & 0xffff0000u);
                uv.w[3] = ((u32)q3 >> 16) | ((u32)(q3 >> 32) & 0xffff0000u);
#pragma unroll
                for (int tl = 0; tl < 6; ++tl)
                    acc[tl] = __builtin_amdgcn_mfma_f32_16x16x32_bf16(uv.v, bf[tl][ks],
                                                                      acc[tl], 0, 0, 0);
            }
            if (grp < 2) {      // rows 0-7 real
#pragma unroll
                for (int tl = 0; tl < 6; ++tl)
#pragma unroll
                    for (int q = 0; q < 4; ++q)
                        part[t & 1][wave][grp * 4 + q][tl * 16 + r16] = acc[tl][q];
            }
        }
        __syncthreads();   // single per-step sync: partials ready, polls joined

        // ---- gate phase (8 waves parallel; wave w owns row w, lanes 0-7 store)
        f32x4 rz = {0.f, 0.f, 0.f, 0.f}, rr = rz, rh = rz;
        if (t > 0) {
#pragma unroll
            for (int w2 = 0; w2 < 8; ++w2) {
                rz += *(const f32x4*)&part[t & 1][w2][wave][c4];
                rr += *(const f32x4*)&part[t & 1][w2][wave][32 + c4];
                rh += *(const f32x4*)&part[t & 1][w2][wave][64 + c4];
            }
        }
        unsigned short hs[4];
#pragma unroll
        for (int i = 0; i < 4; ++i) {
            const float z = 1.f / (1.f + __expf(-(Pl[tokc][c4 + i] + rz[i])));
            const float r = 1.f / (1.f + __expf(-(Pl[tokc][32 + c4 + i] + rr[i])));
            float hh = Pl[tokc][64 + c4 + i] + r * (rh[i] + brh4[i]);
            hh = hh > 0.f ? hh : 0.f;
            const float hnew = z * hreg[i] + (1.f - z) * hh;
            hreg[i] = hnew;
            union { bf16_t h; unsigned short s; } cv; cv.h = (bf16_t)hnew;
            hs[i] = cv.s;
        }
        if (t < kT - 1 && lane < 8) {
            // fire-and-forget tagged publish: NO drain, NO flag (2 MALL hops cut)
            const u32 tg = (u32)(t + 1);
            u64* dst = (u64*)(hsig + (size_t)((t & 1) * kB + myrow) * kH + c0 + c4);
            const u64 lo = ((u64)(tg | ((u32)hs[0] << 16)))
                         | (((u64)(tg | ((u32)hs[1] << 16))) << 32);
            const u64 hi = ((u64)(tg | ((u32)hs[2] << 16)))
                         | (((u64)(tg | ((u32)hs[3] << 16))) << 32);
            __hip_atomic_store(dst,     lo, __ATOMIC_RELAXED, __HIP_MEMORY_SCOPE_AGENT);
            __hip_atomic_store(dst + 1, hi, __ATOMIC_RELAXED, __HIP_MEMORY_SCOPE_AGENT);
        }
        // seq HBM store + token prefetch: off the inter-WG critical path
        if (lane < 8) {
            const u64 sq = (u64)hs[0] | ((u64)hs[1] << 16) | ((u64)hs[2] << 32)
                         | ((u64)hs[3] << 48);
            *(u64*)(seq + ((size_t)myrow * kT + t) * kH + c0 + c4) = sq;
        }
        if (t < kT - 1) tokc = tokens[(size_t)myrow * kT + t + 1];
    }
}

// ---------------- logits = seq @ Wd^T' + bd : 512 WGs x 64 rows
__global__ void k_logits(const bf16_t* __restrict__ seq, const bf16_t* __restrict__ WdT,
                         const float* __restrict__ bd, float* __restrict__ out) {
    const int m0 = blockIdx.x * 64;
    const int lane = threadIdx.x & 63, wave = threadIdx.x >> 6;
    const int r16 = lane & 15, grp = lane >> 4;
    f32x4 acc[8];
#pragma unroll
    for (int n = 0; n < 8; ++n) acc[n] = (f32x4){0.f, 0.f, 0.f, 0.f};
    const bf16_t* ap = seq + (m0 + 16 * wave + r16) * kH + 8 * grp;
    const bf16_t* bp = WdT + r16 * kH + 8 * grp;
    for (int ks = 0; ks < 32; ++ks) {
        const int k0 = 32 * ks;
        bf16x8 a = *(const bf16x8*)(ap + k0);
#pragma unroll
        for (int nt = 0; nt < 8; ++nt) {
            bf16x8 b = *(const bf16x8*)(bp + nt * 16 * kH + k0);
            acc[nt] = __builtin_amdgcn_mfma_f32_16x16x32_bf16(a, b, acc[nt], 0, 0, 0);
        }
    }
#pragma unroll
    for (int nt = 0; nt < 8; ++nt) {
        const int v = 16 * nt + r16;
        const float bias = bd[v];
#pragma unroll
        for (int q = 0; q < 4; ++q) {
            const int m = m0 + 16 * wave + 4 * grp + q;
            out[m * kV + v] = acc[nt][q] + bias;
        }
    }
}

extern "C" void kernel_launch(void* const* d_in, const int* in_sizes, int n_in,
                              void* d_out, int out_size, void* d_ws, size_t ws_size,
                              hipStream_t stream) {
    const int*   tokens = (const int*)d_in[0];
    const float* emb    = (const float*)d_in[1];
    const float* Wx     = (const float*)d_in[2];
    const float* Uh     = (const float*)d_in[3];
    const float* b_in   = (const float*)d_in[4];
    const float* b_rec  = (const float*)d_in[5];
    const float* Wd     = (const float*)d_in[6];
    const float* bd     = (const float*)d_in[7];
    float* out = (float*)d_out;

    char* ws = (char*)d_ws;
    bf16_t* seq  = (bf16_t*)ws;                    // 64*512*1024*2 = 67,108,864 B
    float*  P    = (float*)(ws + 67108864);        // 128*3072*4   =  1,572,864 B
    bf16_t* WdT  = (bf16_t*)(ws + 68681728);       // 128*1024*2   =    262,144 B
    u32*    hsig = (u32*)(ws + 68943872);          // 2*64*1024*4  =    524,288 B

    k_prep_P<<<dim3(12, 4), 256, 0, stream>>>(emb, Wx, b_in, b_rec, P);
    k_prep_WdT<<<512, 256, 0, stream>>>(Wd, WdT);
    hipMemsetAsync(hsig, 0, 524288, stream);       // wipe stale tags every launch
    k_scan<<<256, 512, 0, stream>>>(tokens, Uh, P, b_rec, hsig, seq);
    k_logits<<<512, 256, 0, stream>>>(seq, WdT, bd, out);
}

// Round 13
// 3280.207 us; speedup vs baseline: 1.0145x; 1.0145x over previous
//
#include <hip/hip_runtime.h>
#include <stdint.h>

constexpr int kV = 128, kE = 100, kH = 1024, kB = 64, kT = 512, kH3 = 3072;

typedef __bf16 bf16_t;
typedef __bf16 bf16x8 __attribute__((ext_vector_type(8)));
typedef float f32x4 __attribute__((ext_vector_type(4)));
typedef unsigned int u32;
typedef unsigned long long u64;

// ---------------- P = emb @ Wx + b_in (+ b_rec for z,r gates) : [128][3072] f32
__global__ void k_prep_P(const float* __restrict__ emb, const float* __restrict__ Wx,
                         const float* __restrict__ b_in, const float* __restrict__ b_rec,
                         float* __restrict__ P) {
    const int n = blockIdx.x * 256 + threadIdx.x;   // 12 blocks.x * 256 = 3072
    const int v0 = blockIdx.y * 32;                 // 4 blocks.y
    float wcol[kE];
#pragma unroll
    for (int e = 0; e < kE; ++e) wcol[e] = Wx[e * kH3 + n];
    const float bias = b_in[n] + (n < 2 * kH ? b_rec[n] : 0.f);
    for (int vi = 0; vi < 32; ++vi) {
        const int v = v0 + vi;
        float acc = bias;
#pragma unroll
        for (int e = 0; e < kE; ++e) acc += emb[v * kE + e] * wcol[e];
        P[v * kH3 + n] = acc;
    }
}

// ---------------- WdT = bf16(Wd^T) : [128][1024]
__global__ void k_prep_WdT(const float* __restrict__ Wd, bf16_t* __restrict__ WdT) {
    const int i = blockIdx.x * 256 + threadIdx.x;   // 512 blocks -> 131072
    const int v = i & 127, k = i >> 7;
    WdT[v * kH + k] = (bf16_t)Wd[k * kV + v];
}

// ---------------- persistent GRU scan: tag-in-data, WIDE-ISSUE two-phase poll.
// 256 WGs x 512 thr (8 waves). group g = blockIdx>>5 owns batch rows [8g,8g+8);
// slot = blockIdx&31 owns h-cols [32s,32s+32). h words: (bf16<<16)|tag, tag=t+1.
// Producers: relaxed-AGENT tagged stores, fire-and-forget (no drain/flags).
// Consumers (r12 was 8 SERIAL RTs -> 6.2us/step): phase-1 polls word0 of ALL
// 4 chunks in one issue burst (32B/lane/retry); phase-2 loads the remaining
// 12 u64 wide (one RT), verifies 24 tags, rare retry. ~3 RT total.
// WAR depth-2 ring proof unchanged (r11/r12): per-step __syncthreads joins all
// 8 waves AFTER their polls (union = all 32 slots at tag >= t), so h[t]
// overwrites of h[t-2] follow every WG's completed reads. Tags monotone;
// hsig memset per launch kills cross-replay aliasing.
__launch_bounds__(512, 1)
__global__ void k_scan(const int* __restrict__ tokens, const float* __restrict__ Uh,
                       const float* __restrict__ Pg, const float* __restrict__ b_rec,
                       u32* __restrict__ hsig, bf16_t* __restrict__ seq) {
    __shared__ float Pl[kV][104];          // [v][0:32)=z,[32:64)=r,[64:96)=hh
    __shared__ float part[2][8][8][104];   // [parity][kwave][row][gatecol 0:96)
    const int tid = threadIdx.x;
    const int g = blockIdx.x >> 5, slot = blockIdx.x & 31;
    const int c0 = slot * 32;
    const int lane = tid & 63, wave = tid >> 6;    // 0..7
    const int r16 = lane & 15, grp = lane >> 4;

    // stage P gather table for this WG's 96 gate columns (b_in/b_rec(z,r) folded)
    for (int idx = tid; idx < kV * 96; idx += 512) {
        const int v = idx / 96, gi = idx % 96;
        const int col = (gi >> 5) * kH + c0 + (gi & 31);
        Pl[v][gi] = Pg[v * kH3 + col];
    }
    // B-fragments: 6 tiles x 4 K-steps for this wave's K-slice, register-resident
    bf16x8 bf[6][4];
#pragma unroll
    for (int tile = 0; tile < 6; ++tile) {
        const int col = (tile >> 1) * kH + c0 + (tile & 1) * 16 + r16;
#pragma unroll
        for (int ks = 0; ks < 4; ++ks)
#pragma unroll
            for (int j = 0; j < 8; ++j)
                bf[tile][ks][j] = (bf16_t)Uh[(wave * 128 + ks * 32 + grp * 8 + j) * kH3 + col];
    }
    // gate-phase constants: wave w owns batch row 8g+w; lanes 0-7 x 4 cols at c4
    const int c4 = (lane & 7) * 4;
    const int myrow = 8 * g + wave;
    float brh4[4], hreg[4] = {0.f, 0.f, 0.f, 0.f};
#pragma unroll
    for (int i = 0; i < 4; ++i) brh4[i] = b_rec[2 * kH + c0 + c4 + i];
    int tokc = tokens[(size_t)myrow * kT + 0];
    const int arow = r16 & 7;                      // A-frag row (rows 8-15 dup)
    __syncthreads();

    for (int t = 0; t < kT; ++t) {
        if (t > 0) {
            const u32 tag = (u32)t;
            const u32* hpar = hsig + (size_t)(((t - 1) & 1) * kB + 8 * g + arow) * kH;
            const u64* bp0 = (const u64*)(hpar + wave * 128 + 0 * 32 + grp * 8);
            const u64* bp1 = (const u64*)(hpar + wave * 128 + 1 * 32 + grp * 8);
            const u64* bp2 = (const u64*)(hpar + wave * 128 + 2 * 32 + grp * 8);
            const u64* bp3 = (const u64*)(hpar + wave * 128 + 3 * 32 + grp * 8);
            u64 q[16];
            // ---- phase 1: word0 of ALL 4 chunks, one issue burst per retry
            long guard = 0;
            for (;;) {
                q[0]  = __hip_atomic_load(bp0, __ATOMIC_RELAXED, __HIP_MEMORY_SCOPE_AGENT);
                q[4]  = __hip_atomic_load(bp1, __ATOMIC_RELAXED, __HIP_MEMORY_SCOPE_AGENT);
                q[8]  = __hip_atomic_load(bp2, __ATOMIC_RELAXED, __HIP_MEMORY_SCOPE_AGENT);
                q[12] = __hip_atomic_load(bp3, __ATOMIC_RELAXED, __HIP_MEMORY_SCOPE_AGENT);
                bool ok = true;
#pragma unroll
                for (int i = 0; i < 16; i += 4)
                    ok = ok && ((u32)q[i] & 0xffffu) == tag
                            && ((u32)(q[i] >> 32) & 0xffffu) == tag;
                if (ok) break;
                __builtin_amdgcn_s_sleep(1);
                if (++guard > (1L << 15)) break;   // anti-hang escape
            }
            // ---- phase 2: remaining 12 u64 wide, verify 24 tags (rare retry)
            guard = 0;
            for (;;) {
#pragma unroll
                for (int i = 1; i < 4; ++i) {
                    q[i]      = __hip_atomic_load(bp0 + i, __ATOMIC_RELAXED, __HIP_MEMORY_SCOPE_AGENT);
                    q[4 + i]  = __hip_atomic_load(bp1 + i, __ATOMIC_RELAXED, __HIP_MEMORY_SCOPE_AGENT);
                    q[8 + i]  = __hip_atomic_load(bp2 + i, __ATOMIC_RELAXED, __HIP_MEMORY_SCOPE_AGENT);
                    q[12 + i] = __hip_atomic_load(bp3 + i, __ATOMIC_RELAXED, __HIP_MEMORY_SCOPE_AGENT);
                }
                bool ok = true;
#pragma unroll
                for (int c = 0; c < 16; c += 4)
#pragma unroll
                    for (int i = 1; i < 4; ++i)
                        ok = ok && ((u32)q[c + i] & 0xffffu) == tag
                                && ((u32)(q[c + i] >> 32) & 0xffffu) == tag;
                if (ok) break;
                __builtin_amdgcn_s_sleep(1);
                if (++guard > (1L << 12)) break;   // anti-hang escape
            }
            // ---- unpack hi16 halves (shift/and) -> 4 bf16x8 frags, matmul
            f32x4 acc[6];
#pragma unroll
            for (int tl = 0; tl < 6; ++tl) acc[tl] = (f32x4){0.f, 0.f, 0.f, 0.f};
#pragma unroll
            for (int ks = 0; ks < 4; ++ks) {
                union { u32 w[4]; bf16x8 v; } uv;
#pragma unroll
                for (int i = 0; i < 4; ++i) {
                    const u64 qq = q[ks * 4 + i];
                    uv.w[i] = ((u32)qq >> 16) | ((u32)(qq >> 32) & 0xffff0000u);
                }
#pragma unroll
                for (int tl = 0; tl < 6; ++tl)
                    acc[tl] = __builtin_amdgcn_mfma_f32_16x16x32_bf16(uv.v, bf[tl][ks],
                                                                      acc[tl], 0, 0, 0);
            }
            if (grp < 2) {      // rows 0-7 real
#pragma unroll
                for (int tl = 0; tl < 6; ++tl)
#pragma unroll
                    for (int q2 = 0; q2 < 4; ++q2)
                        part[t & 1][wave][grp * 4 + q2][tl * 16 + r16] = acc[tl][q2];
            }
        }
        __syncthreads();   // single per-step sync: partials ready, polls joined

        // ---- gate phase (8 waves parallel; wave w owns row w, lanes 0-7 store)
        f32x4 rz = {0.f, 0.f, 0.f, 0.f}, rr = rz, rh = rz;
        if (t > 0) {
#pragma unroll
            for (int w2 = 0; w2 < 8; ++w2) {
                rz += *(const f32x4*)&part[t & 1][w2][wave][c4];
                rr += *(const f32x4*)&part[t & 1][w2][wave][32 + c4];
                rh += *(const f32x4*)&part[t & 1][w2][wave][64 + c4];
            }
        }
        unsigned short hs[4];
#pragma unroll
        for (int i = 0; i < 4; ++i) {
            const float z = 1.f / (1.f + __expf(-(Pl[tokc][c4 + i] + rz[i])));
            const float r = 1.f / (1.f + __expf(-(Pl[tokc][32 + c4 + i] + rr[i])));
            float hh = Pl[tokc][64 + c4 + i] + r * (rh[i] + brh4[i]);
            hh = hh > 0.f ? hh : 0.f;
            const float hnew = z * hreg[i] + (1.f - z) * hh;
            hreg[i] = hnew;
            union { bf16_t h; unsigned short s; } cv; cv.h = (bf16_t)hnew;
            hs[i] = cv.s;
        }
        if (t < kT - 1 && lane < 8) {
            // fire-and-forget tagged publish: NO drain, NO flag
            const u32 tg = (u32)(t + 1);
            u64* dst = (u64*)(hsig + (size_t)((t & 1) * kB + myrow) * kH + c0 + c4);
            const u64 lo = ((u64)(tg | ((u32)hs[0] << 16)))
                         | (((u64)(tg | ((u32)hs[1] << 16))) << 32);
            const u64 hi = ((u64)(tg | ((u32)hs[2] << 16)))
                         | (((u64)(tg | ((u32)hs[3] << 16))) << 32);
            __hip_atomic_store(dst,     lo, __ATOMIC_RELAXED, __HIP_MEMORY_SCOPE_AGENT);
            __hip_atomic_store(dst + 1, hi, __ATOMIC_RELAXED, __HIP_MEMORY_SCOPE_AGENT);
        }
        // seq HBM store + token prefetch: off the inter-WG critical path
        if (lane < 8) {
            const u64 sq = (u64)hs[0] | ((u64)hs[1] << 16) | ((u64)hs[2] << 32)
                         | ((u64)hs[3] << 48);
            *(u64*)(seq + ((size_t)myrow * kT + t) * kH + c0 + c4) = sq;
        }
        if (t < kT - 1) tokc = tokens[(size_t)myrow * kT + t + 1];
    }
}

// ---------------- logits = seq @ Wd^T' + bd : 512 WGs x 64 rows
__global__ void k_logits(const bf16_t* __restrict__ seq, const bf16_t* __restrict__ WdT,
                         const float* __restrict__ bd, float* __restrict__ out) {
    const int m0 = blockIdx.x * 64;
    const int lane = threadIdx.x & 63, wave = threadIdx.x >> 6;
    const int r16 = lane & 15, grp = lane >> 4;
    f32x4 acc[8];
#pragma unroll
    for (int n = 0; n < 8; ++n) acc[n] = (f32x4){0.f, 0.f, 0.f, 0.f};
    const bf16_t* ap = seq + (m0 + 16 * wave + r16) * kH + 8 * grp;
    const bf16_t* bp = WdT + r16 * kH + 8 * grp;
    for (int ks = 0; ks < 32; ++ks) {
        const int k0 = 32 * ks;
        bf16x8 a = *(const bf16x8*)(ap + k0);
#pragma unroll
        for (int nt = 0; nt < 8; ++nt) {
            bf16x8 b = *(const bf16x8*)(bp + nt * 16 * kH + k0);
            acc[nt] = __builtin_amdgcn_mfma_f32_16x16x32_bf16(a, b, acc[nt], 0, 0, 0);
        }
    }
#pragma unroll
    for (int nt = 0; nt < 8; ++nt) {
        const int v = 16 * nt + r16;
        const float bias = bd[v];
#pragma unroll
        for (int q = 0; q < 4; ++q) {
            const int m = m0 + 16 * wave + 4 * grp + q;
            out[m * kV + v] = acc[nt][q] + bias;
        }
    }
}

extern "C" void kernel_launch(void* const* d_in, const int* in_sizes, int n_in,
                              void* d_out, int out_size, void* d_ws, size_t ws_size,
                              hipStream_t stream) {
    const int*   tokens = (const int*)d_in[0];
    const float* emb    = (const float*)d_in[1];
    const float* Wx     = (const float*)d_in[2];
    const float* Uh     = (const float*)d_in[3];
    const float* b_in   = (const float*)d_in[4];
    const float* b_rec  = (const float*)d_in[5];
    const float* Wd     = (const float*)d_in[6];
    const float* bd     = (const float*)d_in[7];
    float* out = (float*)d_out;

    char* ws = (char*)d_ws;
    bf16_t* seq  = (bf16_t*)ws;                    // 64*512*1024*2 = 67,108,864 B
    float*  P    = (float*)(ws + 67108864);        // 128*3072*4   =  1,572,864 B
    bf16_t* WdT  = (bf16_t*)(ws + 68681728);       // 128*1024*2   =    262,144 B
    u32*    hsig = (u32*)(ws + 68943872);          // 2*64*1024*4  =    524,288 B

    k_prep_P<<<dim3(12, 4), 256, 0, stream>>>(emb, Wx, b_in, b_rec, P);
    k_prep_WdT<<<512, 256, 0, stream>>>(Wd, WdT);
    hipMemsetAsync(hsig, 0, 524288, stream);       // wipe stale tags every launch
    k_scan<<<256, 512, 0, stream>>>(tokens, Uh, P, b_rec, hsig, seq);
    k_logits<<<512, 256, 0, stream>>>(seq, WdT, bd, out);
}

// Round 15
// 3074.702 us; speedup vs baseline: 1.0824x; 1.0668x over previous
//
#include <hip/hip_runtime.h>
#include <stdint.h>

constexpr int kV = 128, kE = 100, kH = 1024, kB = 64, kT = 512, kH3 = 3072;

typedef __bf16 bf16_t;
typedef __bf16 bf16x8 __attribute__((ext_vector_type(8)));
typedef float f32x4 __attribute__((ext_vector_type(4)));
typedef unsigned int u32;
typedef unsigned long long u64;

// ---------------- P = emb @ Wx + b_in (+ b_rec for z,r gates) : [128][3072] f32
__global__ void k_prep_P(const float* __restrict__ emb, const float* __restrict__ Wx,
                         const float* __restrict__ b_in, const float* __restrict__ b_rec,
                         float* __restrict__ P) {
    const int n = blockIdx.x * 256 + threadIdx.x;   // 12 blocks.x * 256 = 3072
    const int v0 = blockIdx.y * 32;                 // 4 blocks.y
    float wcol[kE];
#pragma unroll
    for (int e = 0; e < kE; ++e) wcol[e] = Wx[e * kH3 + n];
    const float bias = b_in[n] + (n < 2 * kH ? b_rec[n] : 0.f);
    for (int vi = 0; vi < 32; ++vi) {
        const int v = v0 + vi;
        float acc = bias;
#pragma unroll
        for (int e = 0; e < kE; ++e) acc += emb[v * kE + e] * wcol[e];
        P[v * kH3 + n] = acc;
    }
}

// ---------------- WdT = bf16(Wd^T) : [128][1024]
__global__ void k_prep_WdT(const float* __restrict__ Wd, bf16_t* __restrict__ WdT) {
    const int i = blockIdx.x * 256 + threadIdx.x;   // 512 blocks -> 131072
    const int v = i & 127, k = i >> 7;
    WdT[v * kH + k] = (bf16_t)Wd[k * kV + v];
}

// ---------------- persistent GRU scan: r11-green protocol, 16-row groups
// (no MFMA M-waste). 256 WGs x 512 thr (8 waves). group g = blockIdx>>6 owns
// batch rows [16g,16g+16); slot = blockIdx&63 owns h-cols [16s,16s+16).
// Wave w: K-slice [128w,128w+128) -> polls its 8 producer slots x 8 producer
// waves (64 flags, 1/lane, each on its own 128B line); A-loads via relaxed
// AGENT u64 (proven); 12 MFMA/wave/step (all 16 M-rows REAL — r11 wasted half
// on row duplication); gate phase: wave w owns rows (2w,2w+1), 16 lanes x
// (1 row, 2 cols); publish = h-store (relaxed AGENT u32) -> wave vmcnt(0)
// drain -> (slot,wave) flag relaxed (r6/r11-proven pattern).
// r14 bug fixed here: A-load K-step stride is 32 bf16 = 64 B = 8 u64 -> index
// ap + ks*8 (r14 had ks*4, reading half-stride K slices -> absmax 3e-2).
// Depth-2 ring WAR proof unchanged: per-step __syncthreads joins all 8 waves
// AFTER their polls (union = all 64 slots x 8 waves at flag >= t), so h[t]
// overwrites of h[t-2] follow every WG's completed reads of h[t-2]. Flags
// monotone; memset per launch.
__launch_bounds__(512, 1)
__global__ void k_scan(const int* __restrict__ tokens, const float* __restrict__ Uh,
                       const float* __restrict__ Pg, const float* __restrict__ b_rec,
                       bf16_t* __restrict__ hbuf, bf16_t* __restrict__ seq,
                       unsigned* __restrict__ flags) {
    __shared__ float Pl[kV][52];           // [v][0:16)=z,[16:32)=r,[32:48)=hh
    __shared__ float part[2][8][16][52];   // [parity][kwave][row 0:16][gatecol 0:48)
    const int tid = threadIdx.x;
    const int g = blockIdx.x >> 6, slot = blockIdx.x & 63;
    const int c0 = slot * 16;
    const int lane = tid & 63, wave = tid >> 6;    // 0..7
    const int r16 = lane & 15, grp = lane >> 4;

    // stage P gather table for this WG's 48 gate columns (b_in/b_rec(z,r) folded)
    for (int idx = tid; idx < kV * 48; idx += 512) {
        const int v = idx / 48, gi = idx % 48;
        const int col = (gi >> 4) * kH + c0 + (gi & 15);
        Pl[v][gi] = Pg[v * kH3 + col];
    }
    // B-fragments: 3 gate tiles x 4 K-steps -> 48 VGPRs, register-resident
    bf16x8 bf[3][4];
#pragma unroll
    for (int tl = 0; tl < 3; ++tl) {
        const int col = tl * kH + c0 + r16;
#pragma unroll
        for (int ks = 0; ks < 4; ++ks)
#pragma unroll
            for (int j = 0; j < 8; ++j)
                bf[tl][ks][j] = (bf16_t)Uh[(wave * 128 + ks * 32 + grp * 8 + j) * kH3 + col];
    }
    // gate-phase constants: wave w owns rows (2w, 2w+1); lanes 0-15:
    // row = 2w + (lane>>3), col pair cp = (lane&7)*2
    const int rowL = 2 * wave + ((lane >> 3) & 1);
    const int gr = 16 * g + rowL;                  // global batch row
    const int cp = (lane & 7) * 2;
    float brh[2], hreg[2] = {0.f, 0.f};
    brh[0] = b_rec[2 * kH + c0 + cp];
    brh[1] = b_rec[2 * kH + c0 + cp + 1];
    int tokc = (lane < 16) ? tokens[(size_t)gr * kT + 0] : 0;
    __syncthreads();

    for (int t = 0; t < kT; ++t) {
        if (t > 0) {
            // ---- poll: 8 producer slots x 8 producer waves, one flag per lane
            {
                const unsigned* fp = flags +
                    (((size_t)g * 64 + (8 * wave + (lane >> 3))) * 8 + (lane & 7)) * 32;
                long guard = 0;
                while (__hip_atomic_load(fp, __ATOMIC_RELAXED, __HIP_MEMORY_SCOPE_AGENT)
                       < (unsigned)t) {
                    __builtin_amdgcn_s_sleep(1);
                    if (++guard > (1L << 15)) break;   // anti-hang escape
                }
            }
            // ---- A-slice loads (relaxed AGENT u64): row 16g+r16 (ALL rows real)
            // K-step ks covers 32 bf16 = 64 B = 8 u64 (FIX: was ks*4 in r14)
            const bf16_t* hprev = hbuf + (((t & 1) ^ 1) * kB + 16 * g + r16) * kH;
            const u64* ap = (const u64*)(hprev + wave * 128 + grp * 8);
            bf16x8 av[4];
#pragma unroll
            for (int ks = 0; ks < 4; ++ks) {
                union { u64 u[2]; bf16x8 v; } au;
                au.u[0] = __hip_atomic_load(ap + ks * 8, __ATOMIC_RELAXED,
                                            __HIP_MEMORY_SCOPE_AGENT);
                au.u[1] = __hip_atomic_load(ap + ks * 8 + 1, __ATOMIC_RELAXED,
                                            __HIP_MEMORY_SCOPE_AGENT);
                av[ks] = au.v;
            }
            // ---- 12 MFMA (3 gate tiles x 4 ks); D row = grp*4+q (real rows)
            f32x4 acc[3];
#pragma unroll
            for (int tl = 0; tl < 3; ++tl) acc[tl] = (f32x4){0.f, 0.f, 0.f, 0.f};
#pragma unroll
            for (int ks = 0; ks < 4; ++ks)
#pragma unroll
                for (int tl = 0; tl < 3; ++tl)
                    acc[tl] = __builtin_amdgcn_mfma_f32_16x16x32_bf16(av[ks], bf[tl][ks],
                                                                      acc[tl], 0, 0, 0);
#pragma unroll
            for (int tl = 0; tl < 3; ++tl)
#pragma unroll
                for (int q = 0; q < 4; ++q)
                    part[t & 1][wave][grp * 4 + q][tl * 16 + r16] = acc[tl][q];
        }
        __syncthreads();   // single per-step sync: partials ready, polls joined

        // ---- gate phase: 16 lanes x (1 row, 2 cols); 8 waves cover 16 rows
        unsigned short hs[2];
        if (lane < 16) {
            float2 rz = {0.f, 0.f}, rr = rz, rh = rz;
            if (t > 0) {
#pragma unroll
                for (int w2 = 0; w2 < 8; ++w2) {
                    const float* pr = &part[t & 1][w2][rowL][0];
                    const float2 a = *(const float2*)(pr + cp);
                    const float2 b = *(const float2*)(pr + 16 + cp);
                    const float2 c = *(const float2*)(pr + 32 + cp);
                    rz.x += a.x; rz.y += a.y;
                    rr.x += b.x; rr.y += b.y;
                    rh.x += c.x; rh.y += c.y;
                }
            }
            const float2 pz = *(const float2*)&Pl[tokc][cp];
            const float2 pr2 = *(const float2*)&Pl[tokc][16 + cp];
            const float2 ph = *(const float2*)&Pl[tokc][32 + cp];
#pragma unroll
            for (int i = 0; i < 2; ++i) {
                const float xz = i ? pz.y : pz.x, xr = i ? pr2.y : pr2.x, xh = i ? ph.y : ph.x;
                const float az = i ? rz.y : rz.x, ar = i ? rr.y : rr.x, ah = i ? rh.y : rh.x;
                const float z = 1.f / (1.f + __expf(-(xz + az)));
                const float r = 1.f / (1.f + __expf(-(xr + ar)));
                float hh = xh + r * (ah + brh[i]);
                hh = hh > 0.f ? hh : 0.f;
                const float hnew = z * hreg[i] + (1.f - z) * hh;
                hreg[i] = hnew;
                union { bf16_t h; unsigned short s; } cv; cv.h = (bf16_t)hnew;
                hs[i] = cv.s;
            }
            if (t < kT - 1) {
                const u32 hp = (u32)hs[0] | ((u32)hs[1] << 16);
                __hip_atomic_store((u32*)(hbuf + (((t & 1) * kB) + gr) * kH + c0 + cp),
                                   hp, __ATOMIC_RELAXED, __HIP_MEMORY_SCOPE_AGENT);
            }
        }
        if (t < kT - 1) {
            // wave-level drain: all 16 gate lanes' h stores MALL-acked, then publish
            asm volatile("s_waitcnt vmcnt(0)" ::: "memory");
            if (lane == 0)
                __hip_atomic_store(flags + (((size_t)g * 64 + slot) * 8 + wave) * 32,
                                   (unsigned)(t + 1),
                                   __ATOMIC_RELAXED, __HIP_MEMORY_SCOPE_AGENT);
        }
        // seq HBM store + token prefetch: off the inter-WG critical path
        if (lane < 16) {
            *(u32*)(seq + ((size_t)gr * kT + t) * kH + c0 + cp) =
                (u32)hs[0] | ((u32)hs[1] << 16);
            if (t < kT - 1) tokc = tokens[(size_t)gr * kT + t + 1];
        }
    }
}

// ---------------- logits = seq @ Wd^T' + bd : 512 WGs x 64 rows
__global__ void k_logits(const bf16_t* __restrict__ seq, const bf16_t* __restrict__ WdT,
                         const float* __restrict__ bd, float* __restrict__ out) {
    const int m0 = blockIdx.x * 64;
    const int lane = threadIdx.x & 63, wave = threadIdx.x >> 6;
    const int r16 = lane & 15, grp = lane >> 4;
    f32x4 acc[8];
#pragma unroll
    for (int n = 0; n < 8; ++n) acc[n] = (f32x4){0.f, 0.f, 0.f, 0.f};
    const bf16_t* ap = seq + (m0 + 16 * wave + r16) * kH + 8 * grp;
    const bf16_t* bp = WdT + r16 * kH + 8 * grp;
    for (int ks = 0; ks < 32; ++ks) {
        const int k0 = 32 * ks;
        bf16x8 a = *(const bf16x8*)(ap + k0);
#pragma unroll
        for (int nt = 0; nt < 8; ++nt) {
            bf16x8 b = *(const bf16x8*)(bp + nt * 16 * kH + k0);
            acc[nt] = __builtin_amdgcn_mfma_f32_16x16x32_bf16(a, b, acc[nt], 0, 0, 0);
        }
    }
#pragma unroll
    for (int nt = 0; nt < 8; ++nt) {
        const int v = 16 * nt + r16;
        const float bias = bd[v];
#pragma unroll
        for (int q = 0; q < 4; ++q) {
            const int m = m0 + 16 * wave + 4 * grp + q;
            out[m * kV + v] = acc[nt][q] + bias;
        }
    }
}

extern "C" void kernel_launch(void* const* d_in, const int* in_sizes, int n_in,
                              void* d_out, int out_size, void* d_ws, size_t ws_size,
                              hipStream_t stream) {
    const int*   tokens = (const int*)d_in[0];
    const float* emb    = (const float*)d_in[1];
    const float* Wx     = (const float*)d_in[2];
    const float* Uh     = (const float*)d_in[3];
    const float* b_in   = (const float*)d_in[4];
    const float* b_rec  = (const float*)d_in[5];
    const float* Wd     = (const float*)d_in[6];
    const float* bd     = (const float*)d_in[7];
    float* out = (float*)d_out;

    char* ws = (char*)d_ws;
    bf16_t*   seq   = (bf16_t*)ws;                    // 64*512*1024*2 = 67,108,864 B
    float*    P     = (float*)(ws + 67108864);        // 128*3072*4   =  1,572,864 B
    bf16_t*   WdT   = (bf16_t*)(ws + 68681728);       // 128*1024*2   =    262,144 B
    bf16_t*   hbuf  = (bf16_t*)(ws + 68943872);       // 2*64*1024*2  =    262,144 B
    unsigned* flags = (unsigned*)(ws + 69206016);     // 4*64*8 flags x 128B = 262,144 B

    k_prep_P<<<dim3(12, 4), 256, 0, stream>>>(emb, Wx, b_in, b_rec, P);
    k_prep_WdT<<<512, 256, 0, stream>>>(Wd, WdT);
    hipMemsetAsync(flags, 0, 262144, stream);
    k_scan<<<256, 512, 0, stream>>>(tokens, Uh, P, b_rec, hbuf, seq, flags);
    k_logits<<<512, 256, 0, stream>>>(seq, WdT, bd, out);
}

// Round 16
// 2627.823 us; speedup vs baseline: 1.2664x; 1.1701x over previous
//
#include <hip/hip_runtime.h>
#include <stdint.h>

constexpr int kV = 128, kE = 100, kH = 1024, kB = 64, kT = 512, kH3 = 3072;

typedef __bf16 bf16_t;
typedef __bf16 bf16x8 __attribute__((ext_vector_type(8)));
typedef float f32x4 __attribute__((ext_vector_type(4)));
typedef unsigned int u32;
typedef unsigned long long u64;

// ---------------- P = emb @ Wx + b_in (+ b_rec for z,r gates) : [128][3072] f32
__global__ void k_prep_P(const float* __restrict__ emb, const float* __restrict__ Wx,
                         const float* __restrict__ b_in, const float* __restrict__ b_rec,
                         float* __restrict__ P) {
    const int n = blockIdx.x * 256 + threadIdx.x;   // 12 blocks.x * 256 = 3072
    const int v0 = blockIdx.y * 32;                 // 4 blocks.y
    float wcol[kE];
#pragma unroll
    for (int e = 0; e < kE; ++e) wcol[e] = Wx[e * kH3 + n];
    const float bias = b_in[n] + (n < 2 * kH ? b_rec[n] : 0.f);
    for (int vi = 0; vi < 32; ++vi) {
        const int v = v0 + vi;
        float acc = bias;
#pragma unroll
        for (int e = 0; e < kE; ++e) acc += emb[v * kE + e] * wcol[e];
        P[v * kH3 + n] = acc;
    }
}

// ---------------- WdT = bf16(Wd^T) : [128][1024]
__global__ void k_prep_WdT(const float* __restrict__ Wd, bf16_t* __restrict__ WdT) {
    const int i = blockIdx.x * 256 + threadIdx.x;   // 512 blocks -> 131072
    const int v = i & 127, k = i >> 7;
    WdT[v * kH + k] = (bf16_t)Wd[k * kV + v];
}

// ---------------- persistent GRU scan: r11-green + monotone flag cache + setprio.
// 256 WGs x 512 thr (8 waves). group g = blockIdx>>5 owns batch rows [8g,8g+8);
// slot = blockIdx&31 owns h-cols [32s,32s+32). Wave w: K-slice [128w,128w+128)
// -> polls its 4 producer slots x 8 rows (32 flags, 1/lane, each on its own
// 128B line) WITH REGISTER CACHING: flags are monotone, so a lane that ever
// read v >= t skips the poll (MALL RT) entirely. Evidence remains valid for
// both proofs: (data) flag v => h[v-1] visible before that read; (WAR) cached
// v >= t still implies that producer finished reading h[t-2]. A-loads via
// relaxed-AGENT u64 (proven); gate phase (all 8 waves parallel, wave w owns
// row w) runs at s_setprio(1) so publishers preempt other WGs' spinning waves
// (publish latency is on every consumer's critical path); publish = h-store
// (relaxed AGENT u64) -> wave vmcnt(0) drain -> (slot,wave) flag relaxed.
// Depth-2 ring WAR proof unchanged from r11. Flags memset per launch.
__launch_bounds__(512, 1)
__global__ void k_scan(const int* __restrict__ tokens, const float* __restrict__ Uh,
                       const float* __restrict__ Pg, const float* __restrict__ b_rec,
                       bf16_t* __restrict__ hbuf, bf16_t* __restrict__ seq,
                       unsigned* __restrict__ flags) {
    __shared__ float Pl[kV][104];          // [v][0:32)=z,[32:64)=r,[64:96)=hh
    __shared__ float part[2][8][8][104];   // [parity][kwave][row][gatecol 0:96)
    const int tid = threadIdx.x;
    const int g = blockIdx.x >> 5, slot = blockIdx.x & 31;
    const int c0 = slot * 32;
    const int lane = tid & 63, wave = tid >> 6;    // 0..7
    const int r16 = lane & 15, grp = lane >> 4;

    // stage P gather table for this WG's 96 gate columns (b_in/b_rec(z,r) folded)
    for (int idx = tid; idx < kV * 96; idx += 512) {
        const int v = idx / 96, gi = idx % 96;
        const int col = (gi >> 5) * kH + c0 + (gi & 31);
        Pl[v][gi] = Pg[v * kH3 + col];
    }
    // B-fragments: 6 tiles x 4 K-steps for this wave's K-slice, register-resident
    bf16x8 bf[6][4];
#pragma unroll
    for (int tile = 0; tile < 6; ++tile) {
        const int col = (tile >> 1) * kH + c0 + (tile & 1) * 16 + r16;
#pragma unroll
        for (int ks = 0; ks < 4; ++ks)
#pragma unroll
            for (int j = 0; j < 8; ++j)
                bf[tile][ks][j] = (bf16_t)Uh[(wave * 128 + ks * 32 + grp * 8 + j) * kH3 + col];
    }
    // gate-phase constants: wave w owns batch row 8g+w; lanes 0-7 x 4 cols at c4
    const int c4 = (lane & 7) * 4;
    const int myrow = 8 * g + wave;
    float brh4[4], hreg[4] = {0.f, 0.f, 0.f, 0.f};
#pragma unroll
    for (int i = 0; i < 4; ++i) brh4[i] = b_rec[2 * kH + c0 + c4 + i];
    int tokc = tokens[(size_t)myrow * kT + 0];
    const int arow = r16 & 7;                      // A-frag row (rows 8-15 dup)
    const unsigned* fp = flags +
        (((size_t)g * 32 + (wave * 4 + (lane >> 3))) * 8 + (lane & 7)) * 32;
    u32 fcache = 0;                                // monotone flag cache (lanes<32)
    __syncthreads();

    for (int t = 0; t < kT; ++t) {
        if (t > 0) {
            // ---- poll with register cache: skip the MALL RT when cached >= t
            if (lane < 32 && fcache < (u32)t) {
                long guard = 0;
                for (;;) {
                    const u32 v = __hip_atomic_load(fp, __ATOMIC_RELAXED,
                                                    __HIP_MEMORY_SCOPE_AGENT);
                    if (v >= (u32)t) { fcache = v; break; }
                    __builtin_amdgcn_s_sleep(1);
                    if (++guard > (1L << 15)) break;   // anti-hang escape
                }
            }
            // ---- load A-slice (relaxed-AGENT u64, proven), partial matmul
            f32x4 acc[6];
#pragma unroll
            for (int tl = 0; tl < 6; ++tl) acc[tl] = (f32x4){0.f, 0.f, 0.f, 0.f};
            const bf16_t* hprev = hbuf + (((t & 1) ^ 1) * kB + 8 * g) * kH;
            const u64* ap = (const u64*)(hprev + arow * kH + wave * 128 + grp * 8);
            bf16x8 av[4];
#pragma unroll
            for (int ks = 0; ks < 4; ++ks) {
                union { u64 u[2]; bf16x8 v; } au;
                au.u[0] = __hip_atomic_load(ap + ks * 8, __ATOMIC_RELAXED,
                                            __HIP_MEMORY_SCOPE_AGENT);
                au.u[1] = __hip_atomic_load(ap + ks * 8 + 1, __ATOMIC_RELAXED,
                                            __HIP_MEMORY_SCOPE_AGENT);
                av[ks] = au.v;
            }
#pragma unroll
            for (int ks = 0; ks < 4; ++ks)
#pragma unroll
                for (int tl = 0; tl < 6; ++tl)
                    acc[tl] = __builtin_amdgcn_mfma_f32_16x16x32_bf16(av[ks], bf[tl][ks],
                                                                      acc[tl], 0, 0, 0);
            if (grp < 2) {      // rows 0-7 real
#pragma unroll
                for (int tl = 0; tl < 6; ++tl)
#pragma unroll
                    for (int q = 0; q < 4; ++q)
                        part[t & 1][wave][grp * 4 + q][tl * 16 + r16] = acc[tl][q];
            }
        }
        __syncthreads();   // single per-step sync: partials ready, polls joined

        // ---- gate phase at raised priority: publish latency is on every
        // consumer's critical path; preempt other WGs' spinning pollers.
        __builtin_amdgcn_s_setprio(1);
        f32x4 rz = {0.f, 0.f, 0.f, 0.f}, rr = rz, rh = rz;
        if (t > 0) {
#pragma unroll
            for (int w2 = 0; w2 < 8; ++w2) {
                rz += *(const f32x4*)&part[t & 1][w2][wave][c4];
                rr += *(const f32x4*)&part[t & 1][w2][wave][32 + c4];
                rh += *(const f32x4*)&part[t & 1][w2][wave][64 + c4];
            }
        }
        unsigned short hs[4];
#pragma unroll
        for (int i = 0; i < 4; ++i) {
            const float z = 1.f / (1.f + __expf(-(Pl[tokc][c4 + i] + rz[i])));
            const float r = 1.f / (1.f + __expf(-(Pl[tokc][32 + c4 + i] + rr[i])));
            float hh = Pl[tokc][64 + c4 + i] + r * (rh[i] + brh4[i]);
            hh = hh > 0.f ? hh : 0.f;
            const float hnew = z * hreg[i] + (1.f - z) * hh;
            hreg[i] = hnew;
            union { bf16_t h; unsigned short s; } cv; cv.h = (bf16_t)hnew;
            hs[i] = cv.s;
        }
        const u64 hp = (u64)hs[0] | ((u64)hs[1] << 16) | ((u64)hs[2] << 32) | ((u64)hs[3] << 48);
        if (t < kT - 1) {
            if (lane < 8)
                __hip_atomic_store((u64*)(hbuf + (((t & 1) * kB) + myrow) * kH + c0 + c4),
                                   hp, __ATOMIC_RELAXED, __HIP_MEMORY_SCOPE_AGENT);
            // own-wave drain: the 8 lanes' h stores are MALL-acked, then publish
            asm volatile("s_waitcnt vmcnt(0)" ::: "memory");
            if (lane == 0)
                __hip_atomic_store(flags + (((size_t)g * 32 + slot) * 8 + wave) * 32,
                                   (unsigned)(t + 1),
                                   __ATOMIC_RELAXED, __HIP_MEMORY_SCOPE_AGENT);
        }
        __builtin_amdgcn_s_setprio(0);
        // seq HBM store + token prefetch: off the inter-WG critical path
        if (lane < 8)
            *(u64*)(seq + ((size_t)myrow * kT + t) * kH + c0 + c4) = hp;
        if (t < kT - 1) tokc = tokens[(size_t)myrow * kT + t + 1];
    }
}

// ---------------- logits = seq @ Wd^T' + bd : 512 WGs x 64 rows
__global__ void k_logits(const bf16_t* __restrict__ seq, const bf16_t* __restrict__ WdT,
                         const float* __restrict__ bd, float* __restrict__ out) {
    const int m0 = blockIdx.x * 64;
    const int lane = threadIdx.x & 63, wave = threadIdx.x >> 6;
    const int r16 = lane & 15, grp = lane >> 4;
    f32x4 acc[8];
#pragma unroll
    for (int n = 0; n < 8; ++n) acc[n] = (f32x4){0.f, 0.f, 0.f, 0.f};
    const bf16_t* ap = seq + (m0 + 16 * wave + r16) * kH + 8 * grp;
    const bf16_t* bp = WdT + r16 * kH + 8 * grp;
    for (int ks = 0; ks < 32; ++ks) {
        const int k0 = 32 * ks;
        bf16x8 a = *(const bf16x8*)(ap + k0);
#pragma unroll
        for (int nt = 0; nt < 8; ++nt) {
            bf16x8 b = *(const bf16x8*)(bp + nt * 16 * kH + k0);
            acc[nt] = __builtin_amdgcn_mfma_f32_16x16x32_bf16(a, b, acc[nt], 0, 0, 0);
        }
    }
#pragma unroll
    for (int nt = 0; nt < 8; ++nt) {
        const int v = 16 * nt + r16;
        const float bias = bd[v];
#pragma unroll
        for (int q = 0; q < 4; ++q) {
            const int m = m0 + 16 * wave + 4 * grp + q;
            out[m * kV + v] = acc[nt][q] + bias;
        }
    }
}

extern "C" void kernel_launch(void* const* d_in, const int* in_sizes, int n_in,
                              void* d_out, int out_size, void* d_ws, size_t ws_size,
                              hipStream_t stream) {
    const int*   tokens = (const int*)d_in[0];
    const float* emb    = (const float*)d_in[1];
    const float* Wx     = (const float*)d_in[2];
    const float* Uh     = (const float*)d_in[3];
    const float* b_in   = (const float*)d_in[4];
    const float* b_rec  = (const float*)d_in[5];
    const float* Wd     = (const float*)d_in[6];
    const float* bd     = (const float*)d_in[7];
    float* out = (float*)d_out;

    char* ws = (char*)d_ws;
    bf16_t*   seq   = (bf16_t*)ws;                    // 64*512*1024*2 = 67,108,864 B
    float*    P     = (float*)(ws + 67108864);        // 128*3072*4   =  1,572,864 B
    bf16_t*   WdT   = (bf16_t*)(ws + 68681728);       // 128*1024*2   =    262,144 B
    bf16_t*   hbuf  = (bf16_t*)(ws + 68943872);       // 2*64*1024*2  =    262,144 B
    unsigned* flags = (unsigned*)(ws + 69206016);     // 2048 flags x 128 B = 262,144 B

    k_prep_P<<<dim3(12, 4), 256, 0, stream>>>(emb, Wx, b_in, b_rec, P);
    k_prep_WdT<<<512, 256, 0, stream>>>(Wd, WdT);
    hipMemsetAsync(flags, 0, 262144, stream);
    k_scan<<<256, 512, 0, stream>>>(tokens, Uh, P, b_rec, hbuf, seq, flags);
    k_logits<<<512, 256, 0, stream>>>(seq, WdT, bd, out);
}